// Round 1
// 425.546 us; speedup vs baseline: 1.0452x; 1.0452x over previous
//
#include <hip/hip_runtime.h>
#include <stdint.h>

// out[m,n] = sum_k x[m,k]*W[n,k] + sum_r y[m,r]*A[n,r],  y = x @ B^T
// M=256, N=8192, K=8192, R=16. fp32 in/out; bf16 MFMA compute (thr 0.18).
//
// R6: wave remap 4mx2n -> 8mx1n (av redundancy 2x->1x: xb L2/L3 traffic
// 1.07 GB -> 0.53 GB); kz<->XCD-pair affinity swizzle (per-XCD xb slice
// 1 MiB -> L2-resident instead of L3); av loads issued BEFORE W prefetch
// (in-order vmcnt: MFMA wait no longer drains the HBM W loads); pack_y
// folded into the LoRA tail (reads y32 fp32 directly, same RNE pack).

#define DM 256
#define DK 8192
#define DN 8192
#define RLORA 16

#define TN 64
#define BK 64
#define KSPLIT 4
#define KCHUNK (DK / KSPLIT)    // 2048
#define NITER (KCHUNK / BK)     // 32

typedef short bf16x8 __attribute__((ext_vector_type(8)));   // 4 VGPRs
typedef float f32x4v __attribute__((ext_vector_type(4)));

__device__ __forceinline__ unsigned short f2bf(float f) {
  unsigned u = __builtin_bit_cast(unsigned, f);
  u += 0x7FFFu + ((u >> 16) & 1u);           // RNE
  return (unsigned short)(u >> 16);
}

__device__ __forceinline__ bf16x8 pack8(float4 a, float4 b) {
  bf16x8 r;
  r[0] = (short)f2bf(a.x); r[1] = (short)f2bf(a.y);
  r[2] = (short)f2bf(a.z); r[3] = (short)f2bf(a.w);
  r[4] = (short)f2bf(b.x); r[5] = (short)f2bf(b.y);
  r[6] = (short)f2bf(b.z); r[7] = (short)f2bf(b.w);
  return r;
}

// ---------------------------------------------------------------------------
// prep_x: x -> bf16 in frag-linear chunk order, + partial y = x @ B^T.
// Chunk c = (K64*32 + s*16 + g)*64 + (oct*16 + r), 16 B, holding
// x[g*16+r][K64*64 + s*32 + oct*8 .. +8)  (A-operand layout: lane&15=m-row,
// lane>>4=k-octet).  grid (8, 64) x 256 thr.
__global__ __launch_bounds__(256) void prep_x(
    const float* __restrict__ x, const float* __restrict__ Bm,
    unsigned short* __restrict__ xb, float* __restrict__ y32) {
  const int ks = blockIdx.x;
  const int m0 = blockIdx.y * 4;
  const int t = threadIdx.x;
  const int k = ks * 1024 + t * 4;
  const int K64 = k >> 6, s = (k >> 5) & 1, oct = (k >> 3) & 3;
  const int e = k & 7;                       // 0 or 4
  float4 xv[4];
#pragma unroll
  for (int i = 0; i < 4; ++i) {
    const int m = m0 + i;
    const int g = m >> 4, r = m & 15;
    xv[i] = *(const float4*)(x + (size_t)m * DK + k);
    ushort4 h;
    h.x = f2bf(xv[i].x); h.y = f2bf(xv[i].y);
    h.z = f2bf(xv[i].z); h.w = f2bf(xv[i].w);
    const size_t chunk = (size_t)(K64 * 32 + s * 16 + g) * 64 + oct * 16 + r;
    *(ushort4*)(xb + chunk * 8 + e) = h;
  }
  float acc[4][RLORA];
#pragma unroll
  for (int r = 0; r < RLORA; ++r) {
    float4 b = *(const float4*)(Bm + (size_t)r * DK + k);
#pragma unroll
    for (int i = 0; i < 4; ++i)
      acc[i][r] = xv[i].x * b.x + xv[i].y * b.y + xv[i].z * b.z + xv[i].w * b.w;
  }
#pragma unroll
  for (int off = 32; off >= 1; off >>= 1)
#pragma unroll
    for (int i = 0; i < 4; ++i)
#pragma unroll
      for (int r = 0; r < RLORA; ++r)
        acc[i][r] += __shfl_xor(acc[i][r], off, 64);
  __shared__ float red[4][4][RLORA];
  const int lane = t & 63, wv = t >> 6;
  if (lane == 0) {
#pragma unroll
    for (int i = 0; i < 4; ++i)
#pragma unroll
      for (int r = 0; r < RLORA; ++r) red[wv][i][r] = acc[i][r];
  }
  __syncthreads();
  if (t < 64) {
    int i = t >> 4, r = t & 15;
    float sum = red[0][i][r] + red[1][i][r] + red[2][i][r] + red[3][i][r];
    atomicAdd(y32 + (m0 + i) * RLORA + r, sum);
  }
}

// ---------------------------------------------------------------------------
// Main GEMM.  grid 512 x 1 (flat), 512 thr = 8 waves, wave w owns rows
// [w*32, w*32+32) x all TN=64 cols.  kz = XCD-pair (bid&7)>>1 so each XCD
// only touches its 1 MiB xb slice (L2-resident).
__global__ __launch_bounds__(512, 4) void lora_gemm(
    const unsigned short* __restrict__ xb,   // frag-linear bf16 x
    const float* __restrict__ W,             // [8192][8192] fp32
    const float* __restrict__ y32,           // [256][16] fp32
    const float* __restrict__ Aw,            // [8192][16] fp32
    float* __restrict__ out,                 // [256][8192] fp32
    float* __restrict__ part) {              // [KSPLIT][256][8192] or null
  __shared__ unsigned short wsm[2][4096];    // 2 x 8 KB bf16 W-tile

  const int tid = threadIdx.x;
  const int lane = tid & 63, w = tid >> 6;   // w = m-slice 0..7
  const int qr = lane & 15, quad = lane >> 4;

  // XCD-affine decode: xcd = bid&7 (round-robin dispatch), kz fixed per
  // XCD pair, nblk bijective over 0..127 for each kz.
  const int bid = blockIdx.x;
  const int xcd = bid & 7;
  const int kz = xcd >> 1;
  const int nblk = (bid >> 3) + ((xcd & 1) << 6);
  const int n0 = nblk * TN;
  const int kb = kz * KCHUNK;

  // W staging: thread = frag F (=w) x lane slot.  F covers rows
  // n0 + (F&3)*16 + qr, cols (F>>2)*32 + quad*8 .. +8  (32 B).
  const int Fs = w >> 2, Fsub = w & 3;
  const float* wsrc = W + (size_t)(n0 + Fsub * 16 + qr) * DK + kb +
                      Fs * 32 + quad * 8;
  // ds_write dest: (F*64 + lane)*16 = tid*16 -> perfectly linear.
  const unsigned wdst = (unsigned)tid * 16;

  // a-frag stream base: chunk (K64*32 + s*16 + g)*64 + lane, K64 = kz*32+it
  const bf16x8* ap = (const bf16x8*)xb + ((size_t)(kz * 32) * 32) * 64 + lane;

  f32x4v acc[2][4];
#pragma unroll
  for (int a = 0; a < 2; ++a)
#pragma unroll
    for (int b = 0; b < 4; ++b) acc[a][b] = (f32x4v){0.f, 0.f, 0.f, 0.f};

  // prologue: W(0) -> regs -> wsm[0]
  float4 g0 = *(const float4*)(wsrc);
  float4 g1 = *(const float4*)(wsrc + 4);
  *(bf16x8*)((char*)wsm[0] + wdst) = pack8(g0, g1);
  __syncthreads();

  for (int it = 0; it < NITER; ++it) {
    // (1) a-frags FIRST (4 coalesced 16B loads, L2): the MFMA's vmcnt
    // wait then does not chain behind the HBM W prefetch (in-order vmcnt).
    bf16x8 av[2][2];
#pragma unroll
    for (int s = 0; s < 2; ++s)
#pragma unroll
      for (int mt = 0; mt < 2; ++mt)
        av[mt][s] = ap[(size_t)(s * 16 + w * 2 + mt) * 64];
    ap += (size_t)32 * 64;
    // (2) prefetch W(it+1) -- consumed after the MFMA phase
    const bool havW = (it + 1 < NITER);
    if (havW) {
      const float* p = wsrc + (size_t)(it + 1) * BK;
      g0 = *(const float4*)(p);
      g1 = *(const float4*)(p + 4);
    }
    // (3) b-frags from LDS (linear lane*16, conflict-free) + (4) 16 MFMA
    const char* wcur = (const char*)wsm[it & 1];
#pragma unroll
    for (int s = 0; s < 2; ++s) {
      bf16x8 b[4];
#pragma unroll
      for (int sub = 0; sub < 4; ++sub)
        b[sub] = *(const bf16x8*)(wcur + (((s * 4 + sub) * 64 + lane) * 16));
#pragma unroll
      for (int mt = 0; mt < 2; ++mt)
#pragma unroll
        for (int sub = 0; sub < 4; ++sub)
          acc[mt][sub] = __builtin_amdgcn_mfma_f32_16x16x32_bf16(
              av[mt][s], b[sub], acc[mt][sub], 0, 0, 0);
    }
    // (5) pack W(it+1) -> other buffer (vmcnt wait hidden by MFMA phase)
    if (havW) *(bf16x8*)((char*)wsm[(it + 1) & 1] + wdst) = pack8(g0, g1);
    __syncthreads();
  }

  if (kz == 0) {  // LoRA tail: one K=32 MFMA round (cols >=16 zero),
                  // y read straight from y32 fp32 (pack_y folded in).
    const float4 z = {0.f, 0.f, 0.f, 0.f};
    bf16x8 b[4];
#pragma unroll
    for (int sub = 0; sub < 4; ++sub) {
      const float* ap2 = Aw + (size_t)(n0 + sub * 16 + qr) * RLORA + quad * 8;
      float4 p0 = (quad < 2) ? *(const float4*)(ap2) : z;
      float4 p1 = (quad < 2) ? *(const float4*)(ap2 + 4) : z;
      b[sub] = pack8(p0, p1);
    }
#pragma unroll
    for (int mt = 0; mt < 2; ++mt) {
      const float* yp = y32 + (size_t)(w * 32 + mt * 16 + qr) * RLORA + quad * 8;
      float4 q0 = (quad < 2) ? *(const float4*)(yp) : z;
      float4 q1 = (quad < 2) ? *(const float4*)(yp + 4) : z;
      bf16x8 avt = pack8(q0, q1);
#pragma unroll
      for (int sub = 0; sub < 4; ++sub)
        acc[mt][sub] = __builtin_amdgcn_mfma_f32_16x16x32_bf16(
            avt, b[sub], acc[mt][sub], 0, 0, 0);
    }
  }

  // epilogue: C/D col=lane&15 (n), row=quad*4+rg (m)  [m89-verified]
  if (part) {
    float* pb = part + (size_t)kz * DM * DN;
#pragma unroll
    for (int mt = 0; mt < 2; ++mt)
#pragma unroll
      for (int sub = 0; sub < 4; ++sub) {
        float* p = pb + (size_t)(w * 32 + mt * 16 + quad * 4) * DN +
                   n0 + sub * 16 + qr;
#pragma unroll
        for (int rg = 0; rg < 4; ++rg) p[(size_t)rg * DN] = acc[mt][sub][rg];
      }
  } else {
    float* ob = out;
#pragma unroll
    for (int mt = 0; mt < 2; ++mt)
#pragma unroll
      for (int sub = 0; sub < 4; ++sub) {
        float* p = ob + (size_t)(w * 32 + mt * 16 + quad * 4) * DN +
                   n0 + sub * 16 + qr;
#pragma unroll
        for (int rg = 0; rg < 4; ++rg)
          atomicAdd(p + (size_t)rg * DN, acc[mt][sub][rg]);
      }
  }
}

// out = sum_kz part[kz]  (fully overwrites out).  grid 2048 x 256.
__global__ __launch_bounds__(256) void reduce_k(
    const float* __restrict__ part, float* __restrict__ out) {
  size_t i = ((size_t)blockIdx.x * 256 + threadIdx.x) * 4;
  float4 s = *(const float4*)(part + i);
#pragma unroll
  for (int kzi = 1; kzi < KSPLIT; ++kzi) {
    float4 v = *(const float4*)(part + (size_t)kzi * DM * DN + i);
    s.x += v.x; s.y += v.y; s.z += v.z; s.w += v.w;
  }
  *(float4*)(out + i) = s;
}

// ---------------------------------------------------------------------------
extern "C" void kernel_launch(void* const* d_in, const int* in_sizes, int n_in,
                              void* d_out, int out_size, void* d_ws, size_t ws_size,
                              hipStream_t stream) {
  const float* x  = (const float*)d_in[0];   // [4,64,8192]
  const float* W  = (const float*)d_in[1];   // [8192,8192]
  const float* A  = (const float*)d_in[2];   // [8192,16]
  const float* Bm = (const float*)d_in[3];   // [16,8192]
  float* out = (float*)d_out;

  unsigned short* xb = (unsigned short*)d_ws;             // 4 MiB frag-linear
  float* y32 = (float*)((char*)d_ws + (4u << 20));        // 16 KiB
  size_t base_bytes = (4u << 20) + 16384;
  size_t part_bytes = (size_t)KSPLIT * DM * DN * 4;       // 32 MiB
  bool use_part = ws_size >= base_bytes + part_bytes;
  float* part = use_part ? (float*)((char*)d_ws + base_bytes) : nullptr;

  if (!use_part)
    hipMemsetAsync(d_out, 0, (size_t)out_size * sizeof(float), stream);
  hipMemsetAsync(y32, 0, (size_t)DM * RLORA * sizeof(float), stream);
  prep_x<<<dim3(8, 64), 256, 0, stream>>>(x, Bm, xb, y32);
  lora_gemm<<<512, 512, 0, stream>>>(xb, W, y32, A, out, part);
  if (use_part) reduce_k<<<2048, 256, 0, stream>>>(part, out);
}

// Round 2
// 422.038 us; speedup vs baseline: 1.0539x; 1.0083x over previous
//
#include <hip/hip_runtime.h>
#include <stdint.h>

// out[m,n] = sum_k x[m,k]*W[n,k] + sum_r y[m,r]*A[n,r],  y = x @ B^T
// M=256, N=8192, K=8192, R=16. fp32 in/out; bf16 MFMA compute (thr 0.18).
//
// R7: lora_gemm restructured for pure-throughput W streaming:
//  - BK 64->128 (NITER 32->16): half the barriers, 2x in-flight W per iter.
//  - two-deep W prefetch (ping-pong g[2][4], unroll-2 for static indexing):
//    pack(it+1) consumes regs loaded at it-1 (~3200cy earlier) -> the
//    vmcnt wait before each barrier is ~0; HBM latency off the critical path.
//  - load order av0 -> MFMA(s01) -> av1 -> W(it+2) -> MFMA(s23) -> pack:
//    in-order vmcnt never chains an MFMA behind a fresh HBM load, and av
//    halves time-share one 16-VGPR block (peak ~110 regs < 128 cap).
// Carried from R6: 8mx1n waves, kz<->XCD-pair affinity, pack_y folded into
// LoRA tail, frag-linear xb from prep_x.

#define DM 256
#define DK 8192
#define DN 8192
#define RLORA 16

#define TN 64
#define BK 128
#define KSPLIT 4
#define KCHUNK (DK / KSPLIT)    // 2048
#define NITER (KCHUNK / BK)     // 16

typedef short bf16x8 __attribute__((ext_vector_type(8)));   // 4 VGPRs
typedef float f32x4v __attribute__((ext_vector_type(4)));

__device__ __forceinline__ unsigned short f2bf(float f) {
  unsigned u = __builtin_bit_cast(unsigned, f);
  u += 0x7FFFu + ((u >> 16) & 1u);           // RNE
  return (unsigned short)(u >> 16);
}

__device__ __forceinline__ bf16x8 pack8(float4 a, float4 b) {
  bf16x8 r;
  r[0] = (short)f2bf(a.x); r[1] = (short)f2bf(a.y);
  r[2] = (short)f2bf(a.z); r[3] = (short)f2bf(a.w);
  r[4] = (short)f2bf(b.x); r[5] = (short)f2bf(b.y);
  r[6] = (short)f2bf(b.z); r[7] = (short)f2bf(b.w);
  return r;
}

// ---------------------------------------------------------------------------
// prep_x: x -> bf16 in frag-linear chunk order, + partial y = x @ B^T.
// Chunk c = (K64*32 + s*16 + g)*64 + (oct*16 + r), 16 B, holding
// x[g*16+r][K64*64 + s*32 + oct*8 .. +8)  (A-operand layout: lane&15=m-row,
// lane>>4=k-octet).  grid (8, 64) x 256 thr.
__global__ __launch_bounds__(256) void prep_x(
    const float* __restrict__ x, const float* __restrict__ Bm,
    unsigned short* __restrict__ xb, float* __restrict__ y32) {
  const int ks = blockIdx.x;
  const int m0 = blockIdx.y * 4;
  const int t = threadIdx.x;
  const int k = ks * 1024 + t * 4;
  const int K64 = k >> 6, s = (k >> 5) & 1, oct = (k >> 3) & 3;
  const int e = k & 7;                       // 0 or 4
  float4 xv[4];
#pragma unroll
  for (int i = 0; i < 4; ++i) {
    const int m = m0 + i;
    const int g = m >> 4, r = m & 15;
    xv[i] = *(const float4*)(x + (size_t)m * DK + k);
    ushort4 h;
    h.x = f2bf(xv[i].x); h.y = f2bf(xv[i].y);
    h.z = f2bf(xv[i].z); h.w = f2bf(xv[i].w);
    const size_t chunk = (size_t)(K64 * 32 + s * 16 + g) * 64 + oct * 16 + r;
    *(ushort4*)(xb + chunk * 8 + e) = h;
  }
  float acc[4][RLORA];
#pragma unroll
  for (int r = 0; r < RLORA; ++r) {
    float4 b = *(const float4*)(Bm + (size_t)r * DK + k);
#pragma unroll
    for (int i = 0; i < 4; ++i)
      acc[i][r] = xv[i].x * b.x + xv[i].y * b.y + xv[i].z * b.z + xv[i].w * b.w;
  }
#pragma unroll
  for (int off = 32; off >= 1; off >>= 1)
#pragma unroll
    for (int i = 0; i < 4; ++i)
#pragma unroll
      for (int r = 0; r < RLORA; ++r)
        acc[i][r] += __shfl_xor(acc[i][r], off, 64);
  __shared__ float red[4][4][RLORA];
  const int lane = t & 63, wv = t >> 6;
  if (lane == 0) {
#pragma unroll
    for (int i = 0; i < 4; ++i)
#pragma unroll
      for (int r = 0; r < RLORA; ++r) red[wv][i][r] = acc[i][r];
  }
  __syncthreads();
  if (t < 64) {
    int i = t >> 4, r = t & 15;
    float sum = red[0][i][r] + red[1][i][r] + red[2][i][r] + red[3][i][r];
    atomicAdd(y32 + (m0 + i) * RLORA + r, sum);
  }
}

// ---------------------------------------------------------------------------
// Main GEMM.  grid 512 x 1 (flat), 512 thr = 8 waves, wave w owns rows
// [w*32, w*32+32) x all TN=64 cols.  kz = XCD-pair (bid&7)>>1 so each XCD
// only touches its 1 MiB xb slice (L2-resident).
__global__ __launch_bounds__(512, 4) void lora_gemm(
    const unsigned short* __restrict__ xb,   // frag-linear bf16 x
    const float* __restrict__ W,             // [8192][8192] fp32
    const float* __restrict__ y32,           // [256][16] fp32
    const float* __restrict__ Aw,            // [8192][16] fp32
    float* __restrict__ out,                 // [256][8192] fp32
    float* __restrict__ part) {              // [KSPLIT][256][8192] or null
  __shared__ unsigned short wsm[2][8192];    // 2 x 16 KB bf16 W-tile (64n x 128k)

  const int tid = threadIdx.x;
  const int lane = tid & 63, w = tid >> 6;   // w = m-slice 0..7
  const int qr = lane & 15, quad = lane >> 4;

  // XCD-affine decode: xcd = bid&7 (round-robin dispatch), kz fixed per
  // XCD pair, nblk bijective over 0..127 for each kz.
  const int bid = blockIdx.x;
  const int xcd = bid & 7;
  const int kz = xcd >> 1;
  const int nblk = (bid >> 3) + ((xcd & 1) << 6);
  const int n0 = nblk * TN;
  const int kb = kz * KCHUNK;

  // W staging: thread stages frags f0=2w, f1=2w+1.  Frag f holds
  // W[n0 + (f&3)*16 + qr][kb + it*128 + (f>>2)*32 + quad*8 .. +8) as bf16x8
  // at LDS offset f*1024 + lane*16 (linear, conflict-free b128 writes).
  const int f0 = w * 2, f1 = f0 + 1;
  const float* wsrc0 = W + (size_t)(n0 + (f0 & 3) * 16 + qr) * DK + kb +
                       (f0 >> 2) * 32 + quad * 8;
  const float* wsrc1 = W + (size_t)(n0 + (f1 & 3) * 16 + qr) * DK + kb +
                       (f1 >> 2) * 32 + quad * 8;
  const unsigned wdst0 = (unsigned)(f0 * 64 + lane) * 16;
  const unsigned wdst1 = wdst0 + 1024;

  // a-frag stream base: chunk (K64*32 + si*16 + g)*64 + lane, K64 = kz*32 + ...
  const bf16x8* ap = (const bf16x8*)xb + ((size_t)(kz * 32) * 32) * 64 + lane;

  f32x4v acc[2][4];
#pragma unroll
  for (int a = 0; a < 2; ++a)
#pragma unroll
    for (int b = 0; b < 4; ++b) acc[a][b] = (f32x4v){0.f, 0.f, 0.f, 0.f};

  // prologue: W(0) -> g[0] -> wsm[0];  W(1) -> g[1] (packed at it=0).
  float4 g[2][4];
  g[0][0] = *(const float4*)(wsrc0);
  g[0][1] = *(const float4*)(wsrc0 + 4);
  g[0][2] = *(const float4*)(wsrc1);
  g[0][3] = *(const float4*)(wsrc1 + 4);
  g[1][0] = *(const float4*)(wsrc0 + BK);
  g[1][1] = *(const float4*)(wsrc0 + BK + 4);
  g[1][2] = *(const float4*)(wsrc1 + BK);
  g[1][3] = *(const float4*)(wsrc1 + BK + 4);
  *(bf16x8*)((char*)wsm[0] + wdst0) = pack8(g[0][0], g[0][1]);
  *(bf16x8*)((char*)wsm[0] + wdst1) = pack8(g[0][2], g[0][3]);
  __syncthreads();

#pragma unroll 2
  for (int it = 0; it < NITER; ++it) {
    const char* wcur = (const char*)wsm[it & 1];
    // (1) av for k-slices s=0,1 (K64 = it*2): 4 coalesced 16B L2 loads
    bf16x8 av[2][2];
#pragma unroll
    for (int si = 0; si < 2; ++si)
#pragma unroll
      for (int mt = 0; mt < 2; ++mt)
        av[si][mt] =
            ap[(size_t)((it * 2) * 32 + si * 16 + w * 2 + mt) * 64];
    // (2) MFMA s=0,1 (b-frags: linear lane*16 ds_read_b128, conflict-free)
#pragma unroll
    for (int s = 0; s < 2; ++s) {
      bf16x8 b[4];
#pragma unroll
      for (int sub = 0; sub < 4; ++sub)
        b[sub] = *(const bf16x8*)(wcur + (((s * 4 + sub) * 64 + lane) * 16));
#pragma unroll
      for (int mt = 0; mt < 2; ++mt)
#pragma unroll
        for (int sub = 0; sub < 4; ++sub)
          acc[mt][sub] = __builtin_amdgcn_mfma_f32_16x16x32_bf16(
              av[s][mt], b[sub], acc[mt][sub], 0, 0, 0);
    }
    // (3) av for k-slices s=2,3 (K64 = it*2+1) -- BEFORE the W issue so the
    // MFMA vmcnt wait never chains behind the fresh HBM loads (in-order).
#pragma unroll
    for (int si = 0; si < 2; ++si)
#pragma unroll
      for (int mt = 0; mt < 2; ++mt)
        av[si][mt] =
            ap[(size_t)((it * 2 + 1) * 32 + si * 16 + w * 2 + mt) * 64];
    // (4) issue W(it+2) into g[it&1] (W(it) in there was packed at it-1)
    if (it + 2 < NITER) {
      const float* p0 = wsrc0 + (size_t)(it + 2) * BK;
      const float* p1 = wsrc1 + (size_t)(it + 2) * BK;
      g[it & 1][0] = *(const float4*)(p0);
      g[it & 1][1] = *(const float4*)(p0 + 4);
      g[it & 1][2] = *(const float4*)(p1);
      g[it & 1][3] = *(const float4*)(p1 + 4);
    }
    // (5) MFMA s=2,3
#pragma unroll
    for (int s = 2; s < 4; ++s) {
      bf16x8 b[4];
#pragma unroll
      for (int sub = 0; sub < 4; ++sub)
        b[sub] = *(const bf16x8*)(wcur + (((s * 4 + sub) * 64 + lane) * 16));
#pragma unroll
      for (int mt = 0; mt < 2; ++mt)
#pragma unroll
        for (int sub = 0; sub < 4; ++sub)
          acc[mt][sub] = __builtin_amdgcn_mfma_f32_16x16x32_bf16(
              av[s - 2][mt], b[sub], acc[mt][sub], 0, 0, 0);
    }
    // (6) pack W(it+1) from g[(it+1)&1] -- loaded a full iteration ago, so
    // the vmcnt wait here is ~0: the barrier carries no HBM latency.
    if (it + 1 < NITER) {
      char* wnxt = (char*)wsm[(it + 1) & 1];
      *(bf16x8*)(wnxt + wdst0) = pack8(g[(it + 1) & 1][0], g[(it + 1) & 1][1]);
      *(bf16x8*)(wnxt + wdst1) = pack8(g[(it + 1) & 1][2], g[(it + 1) & 1][3]);
    }
    __syncthreads();
  }

  if (kz == 0) {  // LoRA tail: one K=32 MFMA round (cols >=16 zero),
                  // y read straight from y32 fp32 (pack_y folded in).
    const float4 z = {0.f, 0.f, 0.f, 0.f};
    bf16x8 b[4];
#pragma unroll
    for (int sub = 0; sub < 4; ++sub) {
      const float* ap2 = Aw + (size_t)(n0 + sub * 16 + qr) * RLORA + quad * 8;
      float4 p0 = (quad < 2) ? *(const float4*)(ap2) : z;
      float4 p1 = (quad < 2) ? *(const float4*)(ap2 + 4) : z;
      b[sub] = pack8(p0, p1);
    }
#pragma unroll
    for (int mt = 0; mt < 2; ++mt) {
      const float* yp = y32 + (size_t)(w * 32 + mt * 16 + qr) * RLORA + quad * 8;
      float4 q0 = (quad < 2) ? *(const float4*)(yp) : z;
      float4 q1 = (quad < 2) ? *(const float4*)(yp + 4) : z;
      bf16x8 avt = pack8(q0, q1);
#pragma unroll
      for (int sub = 0; sub < 4; ++sub)
        acc[mt][sub] = __builtin_amdgcn_mfma_f32_16x16x32_bf16(
            avt, b[sub], acc[mt][sub], 0, 0, 0);
    }
  }

  // epilogue: C/D col=lane&15 (n), row=quad*4+rg (m)  [m89-verified]
  if (part) {
    float* pb = part + (size_t)kz * DM * DN;
#pragma unroll
    for (int mt = 0; mt < 2; ++mt)
#pragma unroll
      for (int sub = 0; sub < 4; ++sub) {
        float* p = pb + (size_t)(w * 32 + mt * 16 + quad * 4) * DN +
                   n0 + sub * 16 + qr;
#pragma unroll
        for (int rg = 0; rg < 4; ++rg) p[(size_t)rg * DN] = acc[mt][sub][rg];
      }
  } else {
    float* ob = out;
#pragma unroll
    for (int mt = 0; mt < 2; ++mt)
#pragma unroll
      for (int sub = 0; sub < 4; ++sub) {
        float* p = ob + (size_t)(w * 32 + mt * 16 + quad * 4) * DN +
                   n0 + sub * 16 + qr;
#pragma unroll
        for (int rg = 0; rg < 4; ++rg)
          atomicAdd(p + (size_t)rg * DN, acc[mt][sub][rg]);
      }
  }
}

// out = sum_kz part[kz]  (fully overwrites out).  grid 2048 x 256.
__global__ __launch_bounds__(256) void reduce_k(
    const float* __restrict__ part, float* __restrict__ out) {
  size_t i = ((size_t)blockIdx.x * 256 + threadIdx.x) * 4;
  float4 s = *(const float4*)(part + i);
#pragma unroll
  for (int kzi = 1; kzi < KSPLIT; ++kzi) {
    float4 v = *(const float4*)(part + (size_t)kzi * DM * DN + i);
    s.x += v.x; s.y += v.y; s.z += v.z; s.w += v.w;
  }
  *(float4*)(out + i) = s;
}

// ---------------------------------------------------------------------------
extern "C" void kernel_launch(void* const* d_in, const int* in_sizes, int n_in,
                              void* d_out, int out_size, void* d_ws, size_t ws_size,
                              hipStream_t stream) {
  const float* x  = (const float*)d_in[0];   // [4,64,8192]
  const float* W  = (const float*)d_in[1];   // [8192,8192]
  const float* A  = (const float*)d_in[2];   // [8192,16]
  const float* Bm = (const float*)d_in[3];   // [16,8192]
  float* out = (float*)d_out;

  unsigned short* xb = (unsigned short*)d_ws;             // 4 MiB frag-linear
  float* y32 = (float*)((char*)d_ws + (4u << 20));        // 16 KiB
  size_t base_bytes = (4u << 20) + 16384;
  size_t part_bytes = (size_t)KSPLIT * DM * DN * 4;       // 32 MiB
  bool use_part = ws_size >= base_bytes + part_bytes;
  float* part = use_part ? (float*)((char*)d_ws + base_bytes) : nullptr;

  if (!use_part)
    hipMemsetAsync(d_out, 0, (size_t)out_size * sizeof(float), stream);
  hipMemsetAsync(y32, 0, (size_t)DM * RLORA * sizeof(float), stream);
  prep_x<<<dim3(8, 64), 256, 0, stream>>>(x, Bm, xb, y32);
  lora_gemm<<<512, 512, 0, stream>>>(xb, W, y32, A, out, part);
  if (use_part) reduce_k<<<2048, 256, 0, stream>>>(part, out);
}